// Round 2
// baseline (133.861 us; speedup 1.0000x reference)
//
#include <hip/hip_runtime.h>
#include <math.h>

// Reference: B=256 samples; upsample 64/32/16 -> 256x256 (bilinear, align_corners=True),
// sum -> maps; 5x5 gaussian blur (sigma=4, reflect pad); per-sample max -> scores.
// d_out layout: [0:B] = scores, [B:] = maps (B*256*256).
//
// Design: ONE kernel, one block per sample, zero cross-block state, no atomics,
// no init pass — output is a pure function of inputs on every call (graph-replay safe).

static constexpr int W         = 256;  // output width/height
static constexpr int TILE_ROWS = 16;   // rows per strip
static constexpr int GROUPS    = 2;    // strip groups processed in parallel per block
static constexpr int NTHREADS  = W * GROUPS;  // 512

__device__ __forceinline__ int reflect256(int i) {
    // jnp.pad 'reflect': -1 -> 1, -2 -> 2, 256 -> 254, 257 -> 253
    if (i < 0) i = -i;
    if (i > 255) i = 510 - i;
    return i;
}

template<int H>
__device__ __forceinline__ float sample_scale(const float* __restrict__ base,
                                              int ry, int x0, int x1, float fx) {
    // align_corners=True: py = ry*(H-1)/255
    float py = (float)(ry * (H - 1)) / 255.0f;
    int   y0 = (int)py;
    float fy = py - (float)y0;
    int   y1 = min(y0 + 1, H - 1);
    float a = base[y0 * H + x0];
    float b = base[y0 * H + x1];
    float c = base[y1 * H + x0];
    float d = base[y1 * H + x1];
    float top = a + fx * (b - a);
    float bot = c + fx * (d - c);
    return top + fy * (bot - top);
}

__global__ __launch_bounds__(NTHREADS) void fused_kernel(
    const float* __restrict__ in0,   // [B,64,64]
    const float* __restrict__ in1,   // [B,32,32]
    const float* __restrict__ in2,   // [B,16,16]
    float* __restrict__ scores,      // [B]
    float* __restrict__ maps)        // [B,256,256]
{
    const int t   = threadIdx.x;         // column 0..255
    const int g   = threadIdx.y;         // strip group 0..GROUPS-1
    const int b   = blockIdx.x;          // sample
    const int tid = g * W + t;

    __shared__ float s0[64 * 64];        // 16 KB
    __shared__ float s1[32 * 32];        // 4 KB
    __shared__ float s2[16 * 16];        // 1 KB
    __shared__ float vsm[GROUPS][TILE_ROWS][W];  // 32 KB
    __shared__ float red[NTHREADS / 64];

    // Stage this sample's inputs into LDS once.
    const float* __restrict__ gb0 = in0 + (size_t)b * (64 * 64);
    const float* __restrict__ gb1 = in1 + (size_t)b * (32 * 32);
    const float* __restrict__ gb2 = in2 + (size_t)b * (16 * 16);
    for (int i = tid; i < 64 * 64; i += NTHREADS) s0[i] = gb0[i];
    for (int i = tid; i < 32 * 32; i += NTHREADS) s1[i] = gb1[i];
    if (tid < 16 * 16) s2[tid] = gb2[tid];
    __syncthreads();

    // Per-column x-interp params for each scale.
    float px0 = (float)(t * 63) / 255.0f; int x00 = (int)px0; float fx0 = px0 - (float)x00; int x01 = min(x00 + 1, 63);
    float px1 = (float)(t * 31) / 255.0f; int x10 = (int)px1; float fx1 = px1 - (float)x10; int x11 = min(x10 + 1, 31);
    float px2 = (float)(t * 15) / 255.0f; int x20 = (int)px2; float fx2 = px2 - (float)x20; int x21 = min(x20 + 1, 15);

    // Gaussian weights (ksize=5, sigma=4), separable == outer(g,g) 2D conv.
    const float e1 = expf(-1.0f / 32.0f);
    const float e2 = expf(-4.0f / 32.0f);
    const float norm = 1.0f + 2.0f * e1 + 2.0f * e2;
    const float wc = 1.0f / norm, wa = e1 / norm, wb = e2 / norm;

    const int xm2 = reflect256(t - 2), xm1 = reflect256(t - 1);
    const int xp1 = reflect256(t + 1), xp2 = reflect256(t + 2);

    float gmax = -INFINITY;

    for (int ss = 0; ss < (W / TILE_ROWS) / GROUPS; ++ss) {
        const int strip = g + ss * GROUPS;       // group-interleaved strips
        const int r0 = strip * TILE_ROWS;

        // 16 interior rows + 2-row reflected halo, all in registers.
        float m[TILE_ROWS + 4];
#pragma unroll
        for (int lr = 0; lr < TILE_ROWS + 4; ++lr) {
            int ry = reflect256(r0 - 2 + lr);
            float v = sample_scale<64>(s0, ry, x00, x01, fx0)
                    + sample_scale<32>(s1, ry, x10, x11, fx1)
                    + sample_scale<16>(s2, ry, x20, x21, fx2);
            m[lr] = v;
        }

        // maps written exactly once, never re-read.
        float* __restrict__ mout = maps + ((size_t)b * W + r0) * W + t;
#pragma unroll
        for (int i = 0; i < TILE_ROWS; ++i) mout[i * W] = m[i + 2];

        // Protect vsm slab from previous iteration's readers, then vertical 5-tap.
        __syncthreads();
#pragma unroll
        for (int i = 0; i < TILE_ROWS; ++i)
            vsm[g][i][t] = wb * (m[i] + m[i + 4]) + wa * (m[i + 1] + m[i + 3]) + wc * m[i + 2];
        __syncthreads();

        // Horizontal 5-tap (x-reflect at edges), running max.
#pragma unroll
        for (int i = 0; i < TILE_ROWS; ++i) {
            float s = wc * vsm[g][i][t]
                    + wa * (vsm[g][i][xm1] + vsm[g][i][xp1])
                    + wb * (vsm[g][i][xm2] + vsm[g][i][xp2]);
            gmax = fmaxf(gmax, s);
        }
    }

    // Block max reduction: wave64 shuffle, then cross-wave via LDS; thread 0 stores.
#pragma unroll
    for (int off = 32; off > 0; off >>= 1)
        gmax = fmaxf(gmax, __shfl_down(gmax, off));
    if ((tid & 63) == 0) red[tid >> 6] = gmax;
    __syncthreads();
    if (tid == 0) {
        float mx = red[0];
#pragma unroll
        for (int i = 1; i < NTHREADS / 64; ++i) mx = fmaxf(mx, red[i]);
        scores[b] = mx;
    }
}

extern "C" void kernel_launch(void* const* d_in, const int* in_sizes, int n_in,
                              void* d_out, int out_size, void* d_ws, size_t ws_size,
                              hipStream_t stream) {
    const float* in0 = (const float*)d_in[0];
    const float* in1 = (const float*)d_in[1];
    const float* in2 = (const float*)d_in[2];
    const int B = in_sizes[0] / (64 * 64);

    float* scores = (float*)d_out;
    float* maps   = (float*)d_out + B;

    hipLaunchKernelGGL(fused_kernel, dim3(B), dim3(W, GROUPS), 0, stream,
                       in0, in1, in2, scores, maps);
}

// Round 3
// 100.344 us; speedup vs baseline: 1.3340x; 1.3340x over previous
//
#include <hip/hip_runtime.h>
#include <math.h>

// Reference: B=256; upsample 64/32/16 -> 256x256 (bilinear, align_corners=True), sum -> maps;
// 5x5 gaussian blur (sigma=4, reflect); per-sample max -> scores.
// d_out: [0:B] scores, [B:] maps.
//
// Kernel 1: grid = 4 blocks/sample x 64 rows, 256 threads (one column each).
//   - inputs staged to LDS (float4)
//   - rolling separable bilinear: per-scale x-interpolated row pair (rlo,rhi) in
//     registers, reloaded (2 LDS reads) only when the source row advances (uniform branch)
//   - 5-deep register window -> vertical 5-tap -> vsm[16][256]
//   - horizontal 5-tap on column-quads via 3 aligned float4 LDS reads per 4 outputs
//   - block max -> d_ws partials (no atomics, fully rewritten every call)
// Kernel 2: partials -> scores (deterministic).

static constexpr int W  = 256;
static constexpr int QH = 4;            // blocks per sample
static constexpr int ROWS = 64;         // rows per block

__device__ __forceinline__ int reflect256(int i) {
    if (i < 0) i = -i;
    if (i > 255) i = 510 - i;
    return i;
}

template<int H>
__device__ __forceinline__ float sample_direct(const float* __restrict__ base,
                                               int ry, int x0, int x1, float fx) {
    int   iy = ry * (H - 1);
    int   y0 = iy / 255;
    float fy = (float)(iy - 255 * y0) * (1.0f / 255.0f);
    int   y1 = min(y0 + 1, H - 1);
    float a = base[y0 * H + x0];
    float b = base[y0 * H + x1];
    float c = base[y1 * H + x0];
    float d = base[y1 * H + x1];
    float top = a + fx * (b - a);
    float bot = c + fx * (d - c);
    return top + fy * (bot - top);
}

__global__ __launch_bounds__(256, 4) void fused_kernel(
    const float* __restrict__ in0,   // [B,64,64]
    const float* __restrict__ in1,   // [B,32,32]
    const float* __restrict__ in2,   // [B,16,16]
    float* __restrict__ part,        // [B*QH] partial maxes
    float* __restrict__ maps)        // [B,256,256]
{
    const int t   = threadIdx.x;       // column
    const int bid = blockIdx.x;
    const int b   = bid >> 2;
    const int r0  = (bid & 3) * ROWS;

    __shared__ float s0[64 * 64];            // 16 KB
    __shared__ float s1[32 * 32];            // 4 KB
    __shared__ float s2[16 * 16];            // 1 KB
    __shared__ float vsm[16][W];             // 16 KB
    __shared__ float red[4];

    // ---- stage inputs (float4) ----
    {
        const float4* g0 = (const float4*)(in0 + (size_t)b * 4096);
        const float4* g1 = (const float4*)(in1 + (size_t)b * 1024);
        const float4* g2 = (const float4*)(in2 + (size_t)b * 256);
        float4* l0 = (float4*)s0;
        float4* l1 = (float4*)s1;
        float4* l2 = (float4*)s2;
#pragma unroll
        for (int i = 0; i < 4; ++i) l0[t + i * 256] = g0[t + i * 256];
        l1[t] = g1[t];
        if (t < 64) l2[t] = g2[t];
    }
    __syncthreads();

    // ---- per-column x-interp params (integer-exact) ----
    const float inv255 = 1.0f / 255.0f;
    int ix0 = t * 63; int x00 = ix0 / 255; float fx0 = (float)(ix0 - 255 * x00) * inv255; int x01 = min(x00 + 1, 63);
    int ix1 = t * 31; int x10 = ix1 / 255; float fx1 = (float)(ix1 - 255 * x10) * inv255; int x11 = min(x10 + 1, 31);
    int ix2 = t * 15; int x20 = ix2 / 255; float fx2 = (float)(ix2 - 255 * x20) * inv255; int x21 = min(x20 + 1, 15);

    auto xr0 = [&](int y) { float a = s0[y * 64 + x00]; float bb = s0[y * 64 + x01]; return a + fx0 * (bb - a); };
    auto xr1 = [&](int y) { float a = s1[y * 32 + x10]; float bb = s1[y * 32 + x11]; return a + fx1 * (bb - a); };
    auto xr2 = [&](int y) { float a = s2[y * 16 + x20]; float bb = s2[y * 16 + x21]; return a + fx2 * (bb - a); };

    auto direct = [&](int rn) -> float {
        int ry = reflect256(rn);
        return sample_direct<64>(s0, ry, x00, x01, fx0)
             + sample_direct<32>(s1, ry, x10, x11, fx1)
             + sample_direct<16>(s2, ry, x20, x21, fx2);
    };

    // ---- gaussian weights (ksize=5, sigma=4) ----
    const float e1 = expf(-1.0f / 32.0f);
    const float e2 = expf(-4.0f / 32.0f);
    const float nrm = 1.0f + 2.0f * e1 + 2.0f * e2;
    const float wc = 1.0f / nrm, wa = e1 / nrm, wb = e2 / nrm;

    // ---- prime 5-row window: map rows r0-2 .. r0+1 ----
    float m0 = direct(r0 - 2);
    float m1 = direct(r0 - 1);
    float m2 = direct(r0);
    float m3 = direct(r0 + 1);
    // rows r0, r0+1 are this block's to write
    float* __restrict__ mbase = maps + ((size_t)b * W) * W + t;
    mbase[(size_t)(r0) * W]     = m2;
    mbase[(size_t)(r0 + 1) * W] = m3;

    // ---- rolling bilinear state, starting at source row for rn = r0+2 ----
    int iy;
    iy = (r0 + 2) * 63; int ya = iy / 255; int rem0 = iy - ya * 255;
    float rlo0 = xr0(ya), rhi0 = xr0(min(ya + 1, 63));
    iy = (r0 + 2) * 31; int yb = iy / 255; int rem1 = iy - yb * 255;
    float rlo1 = xr1(yb), rhi1 = xr1(min(yb + 1, 31));
    iy = (r0 + 2) * 15; int yc = iy / 255; int rem2 = iy - yc * 255;
    float rlo2 = xr2(yc), rhi2 = xr2(min(yc + 1, 15));

    const int qx = t & 63;          // column-quad index for horizontal phase
    const int c0 = qx * 4;
    const int rowbase = t >> 6;
    const int ca = max(c0 - 4, 0);
    const int cc = min(c0 + 4, 252);

    float gmax = -INFINITY;

    for (int i = 0; i < ROWS; ++i) {
        const int rn = r0 + 2 + i;     // new map row being produced
        float mnew;
        if (rn <= 255) {
            float v0 = rlo0 + (float)rem0 * inv255 * (rhi0 - rlo0);
            float v1 = rlo1 + (float)rem1 * inv255 * (rhi1 - rlo1);
            float v2 = rlo2 + (float)rem2 * inv255 * (rhi2 - rlo2);
            mnew = v0 + v1 + v2;
            // advance (uniform branches; step < 1 so at most one increment)
            rem0 += 63; if (rem0 >= 255) { rem0 -= 255; ya++; rlo0 = rhi0; rhi0 = xr0(min(ya + 1, 63)); }
            rem1 += 31; if (rem1 >= 255) { rem1 -= 255; yb++; rlo1 = rhi1; rhi1 = xr1(min(yb + 1, 31)); }
            rem2 += 15; if (rem2 >= 255) { rem2 -= 255; yc++; rlo2 = rhi2; rhi2 = xr2(min(yc + 1, 15)); }
        } else {
            mnew = direct(rn);         // reflected tail rows 256/257 (top block only)
        }

        if (i < ROWS - 2) {            // rows r0+2 .. r0+63 are ours; r0+64/65 are next block's
            mbase[(size_t)rn * W] = mnew;
        }

        // vertical 5-tap for output row rn-2
        vsm[i & 15][t] = wb * (m0 + mnew) + wa * (m1 + m3) + wc * m2;
        m0 = m1; m1 = m2; m2 = m3; m3 = mnew;

        if ((i & 15) == 15) {
            __syncthreads();
            // horizontal 5-tap over 16 rows x 64 quads; thread -> 4 (row,quad) tasks
#pragma unroll
            for (int k = 0; k < 4; ++k) {
                const int row = rowbase + k * 4;
                const float4 Bv = *(const float4*)&vsm[row][c0];
                const float4 Av = *(const float4*)&vsm[row][ca];
                const float4 Cv = *(const float4*)&vsm[row][cc];
                const float a2 = (qx == 0)  ? Bv.z : Av.z;  // col c0-2 (reflect)
                const float a3 = (qx == 0)  ? Bv.y : Av.w;  // col c0-1
                const float c4 = (qx == 63) ? Bv.z : Cv.x;  // col c0+4
                const float c5 = (qx == 63) ? Bv.y : Cv.y;  // col c0+5
                float o0 = wc * Bv.x + wa * (a3 + Bv.y)   + wb * (a2 + Bv.z);
                float o1 = wc * Bv.y + wa * (Bv.x + Bv.z) + wb * (a3 + Bv.w);
                float o2 = wc * Bv.z + wa * (Bv.y + Bv.w) + wb * (Bv.x + c4);
                float o3 = wc * Bv.w + wa * (Bv.z + c4)   + wb * (Bv.y + c5);
                gmax = fmaxf(gmax, fmaxf(fmaxf(o0, o1), fmaxf(o2, o3)));
            }
            __syncthreads();           // protect vsm for next chunk
        }
    }

    // ---- block max -> partial ----
#pragma unroll
    for (int off = 32; off > 0; off >>= 1)
        gmax = fmaxf(gmax, __shfl_down(gmax, off));
    if ((t & 63) == 0) red[t >> 6] = gmax;
    __syncthreads();
    if (t == 0)
        part[bid] = fmaxf(fmaxf(red[0], red[1]), fmaxf(red[2], red[3]));
}

__global__ void reduce_kernel(const float* __restrict__ part,
                              float* __restrict__ scores, int B) {
    int i = blockIdx.x * blockDim.x + threadIdx.x;
    if (i < B) {
        float m = part[QH * i];
#pragma unroll
        for (int k = 1; k < QH; ++k) m = fmaxf(m, part[QH * i + k]);
        scores[i] = m;
    }
}

extern "C" void kernel_launch(void* const* d_in, const int* in_sizes, int n_in,
                              void* d_out, int out_size, void* d_ws, size_t ws_size,
                              hipStream_t stream) {
    const float* in0 = (const float*)d_in[0];
    const float* in1 = (const float*)d_in[1];
    const float* in2 = (const float*)d_in[2];
    const int B = in_sizes[0] / (64 * 64);

    float* scores = (float*)d_out;
    float* maps   = (float*)d_out + B;
    float* part   = (float*)d_ws;          // B*QH floats, fully rewritten each call

    hipLaunchKernelGGL(fused_kernel, dim3(B * QH), dim3(256), 0, stream,
                       in0, in1, in2, part, maps);
    hipLaunchKernelGGL(reduce_kernel, dim3((B + 255) / 256), dim3(256), 0, stream,
                       part, scores, B);
}